// Round 2
// baseline (9345.043 us; speedup 1.0000x reference)
//
#include <hip/hip_runtime.h>
#include <math.h>

// LSTM: B=128, T=1024, D=64, H=256, C=6
// Fused persistent kernel: one workgroup per batch element (128 wgs x 1024 threads).
// Thread j owns gate column j (4H = 1024 columns).
//  - Wx column (64 floats) preloaded in registers per thread -> no per-step Wx traffic
//  - Wh streamed from L2 each step (1 MB/step/wg)  <-- expected bottleneck this round
//  - h, activated gates, x row staged in LDS; c state in registers (threads < 256)
//  - output projection (6 classes) fused: 6 waves do shuffle-reduced dot(h, Wout[:,c])
// R1 fix: wout_t staging was a single guarded load for 1536 elements with only
// 1024 threads -> rows m>=171 uninitialized -> absmax 2.48. Now strided loop.

#define Bb 128
#define Tt 1024
#define Dd 64
#define Hh 256
#define G4 1024   // 4*H
#define Cc 6

__global__ __launch_bounds__(1024) void lstm_fused(
    const float* __restrict__ x,     // [B,T,D]
    const float* __restrict__ Wx,    // [D,4H]
    const float* __restrict__ Wh,    // [H,4H]
    const float* __restrict__ bias,  // [4H]
    const float* __restrict__ Wout,  // [H,C]
    const float* __restrict__ bout,  // [C]
    float* __restrict__ out)         // [B,T,C]
{
    __shared__ float h_lds[Hh];
    __shared__ float gates_lds[G4];
    __shared__ float x_lds[2][Dd];
    __shared__ float wout_t[Cc][Hh];  // wout_t[c][m] = Wout[m][c]
    __shared__ float bout_l[Cc];

    const int tid = threadIdx.x;
    const int b   = blockIdx.x;

    // --- prologue ---------------------------------------------------------
    // preload this thread's Wx column + bias into registers
    float wx[Dd];
    #pragma unroll
    for (int d = 0; d < Dd; ++d) wx[d] = Wx[d * G4 + tid];
    const float bj = bias[tid];

    if (tid < Hh) h_lds[tid] = 0.0f;
    for (int i = tid; i < Cc * Hh; i += 1024)    // R1 fix: strided (1536 > 1024)
        wout_t[i % Cc][i / Cc] = Wout[i];        // Wout flat [m][c], i = m*6+c
    if (tid < Cc) bout_l[tid] = bout[tid];
    const float* xB = x + (long)b * Tt * Dd;
    if (tid < Dd) x_lds[0][tid] = xB[tid];  // x row for t=0
    float c_state = 0.0f;
    __syncthreads();

    const float* WhB = Wh + tid;  // column j base; loads are lane-coalesced

    // --- time loop --------------------------------------------------------
    for (int t = 0; t < Tt; ++t) {
        // phase A: gate pre-activation  g = b[j] + x_t . Wx[:,j] + h . Wh[:,j]
        float g = bj;
        const float* xr = x_lds[t & 1];
        #pragma unroll
        for (int d = 0; d < Dd; ++d) g += xr[d] * wx[d];

        #pragma unroll 8
        for (int k = 0; k < Hh; ++k) g += h_lds[k] * WhB[k * G4];

        // activation (wave-uniform branches: groups of 256 threads = 4 waves)
        float a;
        if (tid < 2 * Hh)      a = 1.0f / (1.0f + expf(-g));  // i, f
        else if (tid < 3 * Hh) a = tanhf(g);                  // g
        else                   a = 1.0f / (1.0f + expf(-g));  // o
        gates_lds[tid] = a;
        __syncthreads();  // barrier 1

        // phase B: state update (threads < 256); x prefetch (threads 384..447)
        if (tid < Hh) {
            float iv = gates_lds[tid];
            float fv = gates_lds[tid + Hh];
            float gv = gates_lds[tid + 2 * Hh];
            float ov = gates_lds[tid + 3 * Hh];
            c_state = fv * c_state + iv * gv;
            h_lds[tid] = ov * tanhf(c_state);
        } else if (tid >= 384 && tid < 448) {
            int tn = t + 1;
            if (tn < Tt) x_lds[tn & 1][tid - 384] = xB[(long)tn * Dd + (tid - 384)];
        }
        __syncthreads();  // barrier 2

        // phase C: fused output projection for step t (waves 0..5), overlaps
        // with other waves starting the next step's phase A.
        const int w = tid >> 6, l = tid & 63;
        if (w < Cc) {
            float p = 0.0f;
            #pragma unroll
            for (int q = 0; q < 4; ++q) {
                int m = l + 64 * q;
                p += h_lds[m] * wout_t[w][m];
            }
            #pragma unroll
            for (int off = 32; off > 0; off >>= 1)
                p += __shfl_down(p, off);
            if (l == 0) out[((long)b * Tt + t) * Cc + w] = p + bout_l[w];
        }
        // h_lds next written in phase B(t+1), which is behind barrier 1(t+1):
        // waves 0..5 reach it only after finishing phase C -> no race.
    }
}

extern "C" void kernel_launch(void* const* d_in, const int* in_sizes, int n_in,
                              void* d_out, int out_size, void* d_ws, size_t ws_size,
                              hipStream_t stream) {
    const float* x    = (const float*)d_in[0];
    const float* Wx   = (const float*)d_in[1];
    const float* Wh   = (const float*)d_in[2];
    const float* bvec = (const float*)d_in[3];
    const float* Wout = (const float*)d_in[4];
    const float* bout = (const float*)d_in[5];
    float* out = (float*)d_out;

    lstm_fused<<<dim3(Bb), dim3(1024), 0, stream>>>(x, Wx, Wh, bvec, Wout, bout, out);
}

// Round 3
// 8803.371 us; speedup vs baseline: 1.0615x; 1.0615x over previous
//
#include <hip/hip_runtime.h>
#include <math.h>

// LSTM B=128,T=1024,D=64,H=256,C=6 — weight-stationary cooperative kernel.
// 256 wgs x 1024 thr (1 wg/CU). Group = 4 wgs <-> one batch PAIR.
// wg slice: 64 units x 4 gates = 256 cols; Wh slice in registers
// (64 VGPR/thread, 4-way k-split, shuffle-reduce). Per-step h exchange
// through d_ws with agent-scope atomics + parity-double-buffered flags.

#define Bb 128
#define Tt 1024
#define Dd 64
#define Hh 256
#define G4 1024
#define Cc 6
#define NGRP 64
// ws layout: [0,512) int flags[NGRP][2]; [512, 512+256K) float hbuf[NGRP][2][2][Hh]
#define WS_NEED (512 + NGRP*2*2*Hh*4)

__global__ void zero_flags(int* flags) {
    if (threadIdx.x < NGRP * 2) flags[threadIdx.x] = 0;
}

__global__ __launch_bounds__(1024, 4) void lstm_ws(
    const float* __restrict__ x, const float* __restrict__ Wx,
    const float* __restrict__ Wh, const float* __restrict__ bias,
    const float* __restrict__ Wout, const float* __restrict__ bout,
    float* __restrict__ out, int* __restrict__ flags, float* __restrict__ hbuf)
{
    __shared__ float h_lds[2][Hh];        // [batch][unit], current h
    __shared__ float gl[2][4][64];        // gate exchange [b][gate][u_loc]
    __shared__ float x_lds[2][2][Dd];     // [parity][b][d]
    __shared__ float wout_t[Cc][Hh];
    __shared__ float bout_l[Cc];

    const int tid = threadIdx.x;
    const int bid = blockIdx.x;
    const int g   = bid & 63;        // group — bid&7 equal within group -> same XCD
    const int sp  = bid >> 6;        // slice 0..3
    const int b0  = 2 * g;

    const int lc   = tid >> 2;       // local col 0..255
    const int ks   = tid & 3;        // k-quarter
    const int q    = lc >> 6;        // gate (wave-uniform)
    const int uloc = lc & 63;
    const int col  = 256 * q + 64 * sp + uloc;

    int*   flg = flags + g * 2;
    float* hb  = hbuf + g * (2 * 2 * Hh);   // [(par*2+b)*Hh + u]

    // ---- prologue: weights in registers (staggered k order) ----
    float4 w4[16];
    #pragma unroll
    for (int kk = 0; kk < 16; ++kk) {
        int k = 64 * ks + ((4 * kk + 8 * ks) & 63);
        w4[kk].x = Wh[(k + 0) * G4 + col];
        w4[kk].y = Wh[(k + 1) * G4 + col];
        w4[kk].z = Wh[(k + 2) * G4 + col];
        w4[kk].w = Wh[(k + 3) * G4 + col];
    }
    float wx[16];
    #pragma unroll
    for (int dd = 0; dd < 16; ++dd) wx[dd] = Wx[(16 * ks + dd) * G4 + col];
    const float bj = bias[col];

    if (tid < 2 * Hh) h_lds[tid >> 8][tid & 255] = 0.0f;
    for (int i = tid; i < Cc * Hh; i += 1024) wout_t[i % Cc][i / Cc] = Wout[i];
    if (tid < Cc) bout_l[tid] = bout[tid];
    if (tid < 128)
        x_lds[0][tid >> 6][tid & 63] = x[(long)(b0 + (tid >> 6)) * Tt * Dd + (tid & 63)];
    float c_state = 0.0f;
    __syncthreads();

    for (int t = 0; t < Tt; ++t) {
        const int par = t & 1;
        // ---- phase A: gate preactivations ----
        float a0 = 0.0f, a1 = 0.0f;
        {
            const float4* xr0 = (const float4*)&x_lds[par][0][16 * ks];
            const float4* xr1 = (const float4*)&x_lds[par][1][16 * ks];
            #pragma unroll
            for (int j = 0; j < 4; ++j) {
                float4 v0 = xr0[j], v1 = xr1[j];
                a0 += v0.x * wx[4*j] + v0.y * wx[4*j+1] + v0.z * wx[4*j+2] + v0.w * wx[4*j+3];
                a1 += v1.x * wx[4*j] + v1.y * wx[4*j+1] + v1.z * wx[4*j+2] + v1.w * wx[4*j+3];
            }
        }
        const float4* h40 = (const float4*)h_lds[0];
        const float4* h41 = (const float4*)h_lds[1];
        #pragma unroll
        for (int kk = 0; kk < 16; ++kk) {
            int idx = 16 * ks + ((kk + 2 * ks) & 15);  // bank-staggered
            float4 hv0 = h40[idx], hv1 = h41[idx];
            float4 ww = w4[kk];
            a0 += hv0.x * ww.x + hv0.y * ww.y + hv0.z * ww.z + hv0.w * ww.w;
            a1 += hv1.x * ww.x + hv1.y * ww.y + hv1.z * ww.z + hv1.w * ww.w;
        }
        a0 += __shfl_xor(a0, 1); a0 += __shfl_xor(a0, 2);
        a1 += __shfl_xor(a1, 1); a1 += __shfl_xor(a1, 2);
        if (ks == 0) {
            float p0 = a0 + bj, p1 = a1 + bj, r0, r1;
            if (q == 2) { r0 = tanhf(p0); r1 = tanhf(p1); }
            else        { r0 = 1.0f / (1.0f + expf(-p0)); r1 = 1.0f / (1.0f + expf(-p1)); }
            gl[0][q][uloc] = r0; gl[1][q][uloc] = r1;
        }
        __syncthreads();  // B1: gates ready

        // ---- phase B: state update + publish; x prefetch ----
        if (tid < 128) {
            int bb = tid >> 6, uu = tid & 63;
            float iv = gl[bb][0][uu], fv = gl[bb][1][uu];
            float gv = gl[bb][2][uu], ov = gl[bb][3][uu];
            c_state = fv * c_state + iv * gv;
            float hv = ov * tanhf(c_state);
            __hip_atomic_store(&hb[(par * 2 + bb) * Hh + 64 * sp + uu], hv,
                               __ATOMIC_RELAXED, __HIP_MEMORY_SCOPE_AGENT);
        } else if (tid >= 512 && tid < 640) {
            int tn = t + 1;
            if (tn < Tt) {
                int bb = (tid - 512) >> 6, d = tid & 63;
                x_lds[tn & 1][bb][d] = x[((long)(b0 + bb) * Tt + tn) * Dd + d];
            }
        }
        __syncthreads();  // B2: drains the agent stores (vmcnt(0) before barrier)

        if (tid == 0) {
            __hip_atomic_fetch_add(&flg[par], 1, __ATOMIC_RELEASE, __HIP_MEMORY_SCOPE_AGENT);
            int target = 4 * ((t >> 1) + 1);
            for (int spin = 0; spin < (1 << 24); ++spin) {
                if (__hip_atomic_load(&flg[par], __ATOMIC_ACQUIRE,
                                      __HIP_MEMORY_SCOPE_AGENT) >= target) break;
                __builtin_amdgcn_s_sleep(2);
            }
        }
        __syncthreads();  // B3: all 4 slices posted

        if (tid < 512) {
            int bb = tid >> 8, uu = tid & 255;
            h_lds[bb][uu] = __hip_atomic_load(&hb[(par * 2 + bb) * Hh + uu],
                                              __ATOMIC_RELAXED, __HIP_MEMORY_SCOPE_AGENT);
        }
        __syncthreads();  // B4: h(t) staged

        // ---- phase C: output projection (slices 0,1 only) ----
        if (sp < 2) {
            int w6 = tid >> 6, l = tid & 63;
            if (w6 < Cc) {
                float p = 0.0f;
                #pragma unroll
                for (int mj = 0; mj < 4; ++mj)
                    p += h_lds[sp][l + 64 * mj] * wout_t[w6][l + 64 * mj];
                #pragma unroll
                for (int off = 32; off > 0; off >>= 1) p += __shfl_down(p, off);
                if (l == 0) out[((long)(b0 + sp) * Tt + t) * Cc + w6] = p + bout_l[w6];
            }
        }
    }
}

// ---------------- fallback (R2 kernel, used if ws too small) ----------------
__global__ __launch_bounds__(1024) void lstm_fused(
    const float* __restrict__ x, const float* __restrict__ Wx,
    const float* __restrict__ Wh, const float* __restrict__ bias,
    const float* __restrict__ Wout, const float* __restrict__ bout,
    float* __restrict__ out)
{
    __shared__ float h_lds[Hh];
    __shared__ float gates_lds[G4];
    __shared__ float x_lds[2][Dd];
    __shared__ float wout_t[Cc][Hh];
    __shared__ float bout_l[Cc];
    const int tid = threadIdx.x;
    const int b   = blockIdx.x;
    float wx[Dd];
    #pragma unroll
    for (int d = 0; d < Dd; ++d) wx[d] = Wx[d * G4 + tid];
    const float bj = bias[tid];
    if (tid < Hh) h_lds[tid] = 0.0f;
    for (int i = tid; i < Cc * Hh; i += 1024) wout_t[i % Cc][i / Cc] = Wout[i];
    if (tid < Cc) bout_l[tid] = bout[tid];
    const float* xB = x + (long)b * Tt * Dd;
    if (tid < Dd) x_lds[0][tid] = xB[tid];
    float c_state = 0.0f;
    __syncthreads();
    const float* WhB = Wh + tid;
    for (int t = 0; t < Tt; ++t) {
        float gg = bj;
        const float* xr = x_lds[t & 1];
        #pragma unroll
        for (int d = 0; d < Dd; ++d) gg += xr[d] * wx[d];
        #pragma unroll 8
        for (int k = 0; k < Hh; ++k) gg += h_lds[k] * WhB[k * G4];
        float a;
        if (tid < 2 * Hh)      a = 1.0f / (1.0f + expf(-gg));
        else if (tid < 3 * Hh) a = tanhf(gg);
        else                   a = 1.0f / (1.0f + expf(-gg));
        gates_lds[tid] = a;
        __syncthreads();
        if (tid < Hh) {
            float iv = gates_lds[tid], fv = gates_lds[tid + Hh];
            float gv = gates_lds[tid + 2 * Hh], ov = gates_lds[tid + 3 * Hh];
            c_state = fv * c_state + iv * gv;
            h_lds[tid] = ov * tanhf(c_state);
        } else if (tid >= 384 && tid < 448) {
            int tn = t + 1;
            if (tn < Tt) x_lds[tn & 1][tid - 384] = xB[(long)tn * Dd + (tid - 384)];
        }
        __syncthreads();
        const int w = tid >> 6, l = tid & 63;
        if (w < Cc) {
            float p = 0.0f;
            #pragma unroll
            for (int qq = 0; qq < 4; ++qq) p += h_lds[l + 64 * qq] * wout_t[w][l + 64 * qq];
            #pragma unroll
            for (int off = 32; off > 0; off >>= 1) p += __shfl_down(p, off);
            if (l == 0) out[((long)b * Tt + t) * Cc + w] = p + bout_l[w];
        }
    }
}

extern "C" void kernel_launch(void* const* d_in, const int* in_sizes, int n_in,
                              void* d_out, int out_size, void* d_ws, size_t ws_size,
                              hipStream_t stream) {
    const float* x    = (const float*)d_in[0];
    const float* Wx   = (const float*)d_in[1];
    const float* Wh   = (const float*)d_in[2];
    const float* bvec = (const float*)d_in[3];
    const float* Wout = (const float*)d_in[4];
    const float* bout = (const float*)d_in[5];
    float* outp = (float*)d_out;

    if (ws_size >= (size_t)WS_NEED) {
        int*   flags = (int*)d_ws;
        float* hbuf  = (float*)((char*)d_ws + 512);
        zero_flags<<<dim3(1), dim3(128), 0, stream>>>(flags);
        void* args[] = { (void*)&x, (void*)&Wx, (void*)&Wh, (void*)&bvec,
                         (void*)&Wout, (void*)&bout, (void*)&outp,
                         (void*)&flags, (void*)&hbuf };
        hipLaunchCooperativeKernel((void*)lstm_ws, dim3(256), dim3(1024),
                                   args, 0, stream);
    } else {
        lstm_fused<<<dim3(Bb), dim3(1024), 0, stream>>>(x, Wx, Wh, bvec, Wout, bout, outp);
    }
}